// Round 9
// baseline (238.190 us; speedup 1.0000x reference)
//
#include <hip/hip_runtime.h>

#define N_TOKENS 32768
#define K_CODES  1024
#define DIM      256
#define BETA     0.25f

typedef unsigned long long u64;
typedef _Float16 half8 __attribute__((ext_vector_type(8)));
typedef _Float16 half4 __attribute__((ext_vector_type(4)));
typedef float floatx4 __attribute__((ext_vector_type(4)));

// XOR swizzle (verified on HW in r7/r8): 16-B granule g of row r stored at
// granule g ^ ((r ^ r>>2) & 3). Frag reads and staging stores both 2-way
// bank-aliased (free, m136) while keeping 16-B alignment for b128.
__device__ __forceinline__ int gsw(int row, int g) {
    return g ^ ((row ^ (row >> 2)) & 3);
}

// ---- init: wn[k]=||w_k||^2 (deterministic order), counts=0, keys=+inf,
//      done=0, and w -> hi/lo fp16 LDS-image layout (wPack).
// wPack image for (eighth e, chunk c): 8192 halves = [hi 4096 | lo 4096];
// hi[r*32 + gsw(r,g)*8 + e] = (fp16)w[e*128+r][c*32+g*8+e].
__global__ void init_kernel(const float* __restrict__ w, float* __restrict__ wn,
                            int* __restrict__ counts, u64* __restrict__ keys,
                            unsigned* __restrict__ done,
                            _Float16* __restrict__ wPack) {
    int k = blockIdx.x;
    int lane = threadIdx.x;  // 64
    float4 v = *(const float4*)(w + (size_t)k * DIM + lane * 4);
    float vals[4] = {v.x, v.y, v.z, v.w};
    float s = 0.f;
    half4 hv, lv;
    #pragma unroll
    for (int e = 0; e < 4; e++) {
        s += vals[e] * vals[e];
        _Float16 h = (_Float16)vals[e];
        hv[e] = h;
        lv[e] = (_Float16)(vals[e] - (float)h);
    }
    int e8 = k >> 7, r = k & 127;
    int c = lane >> 3, g = (lane & 7) >> 1, eo = (lane & 1) * 4;
    size_t base = (size_t)(e8 * 8 + c) * 8192 + r * 32 + gsw(r, g) * 8 + eo;
    *(half4*)&wPack[base] = hv;
    *(half4*)&wPack[base + 4096] = lv;
    #pragma unroll
    for (int off = 32; off; off >>= 1) s += __shfl_down(s, off);
    if (lane == 0) { wn[k] = s; counts[k] = 0; }
    if (k == 0 && lane == 0) *done = 0u;
    if (lane < 32) keys[k * 32 + lane] = ~0ull;   // 1024*32 = 32768 keys
}

// ---- prep_z: z -> hi/lo fp16 LDS-image layout (zPack, in z_q output region).
// Image for (tile t, chunk c): 8192 halves [hi 4096 | lo 4096], same formula.
// grid = 256 tiles x 4 chunk-pairs; memory-bound (~64 MB moved).
__global__ void prep_z_kernel(const float* __restrict__ z,
                              _Float16* __restrict__ zPack) {
    int tid = threadIdx.x;
    int t = blockIdx.x >> 2, p = blockIdx.x & 3;
    #pragma unroll
    for (int cc = 0; cc < 2; cc++) {
        int c = p * 2 + cc;
        #pragma unroll
        for (int j = 0; j < 2; j++) {
            int idx = j * 256 + tid;
            int r = idx >> 2, g = idx & 3;
            const float* src = z + (size_t)(t * 128 + r) * DIM + c * 32 + g * 8;
            float4 a = *(const float4*)src;
            float4 b = *(const float4*)(src + 4);
            float vals[8] = {a.x, a.y, a.z, a.w, b.x, b.y, b.z, b.w};
            half8 hv, lv;
            #pragma unroll
            for (int e = 0; e < 8; e++) {
                _Float16 h = (_Float16)vals[e];
                hv[e] = h;
                lv[e] = (_Float16)(vals[e] - (float)h);
            }
            size_t base = (size_t)(t * 8 + c) * 8192 + r * 32 + gsw(r, g) * 8;
            *(half8*)&zPack[base] = hv;
            *(half8*)&zPack[base + 4096] = lv;
        }
    }
}

// ---------------- argmin: fp16-split MFMA distance GEMM + atomicMin merge ----
// dot(z,w) = hi_z*hi_w + hi_z*lo_w + lo_z*hi_w  (lo*lo dropped, err ~1e-5).
// grid = 8 code-eighths x 256 token-tiles. Block: 128 tok x 128 codes, 4 waves,
// wave tile 64x64, acc = 64 AGPR + ~70 VGPR -> 3 waves/SIMD; LDS 32 KB.
// Staging is now PURE COPY from pre-split images (r8 lesson: in-loop fp32->fp16
// conversion was ~12 us of redundant VALU on the inter-barrier critical path).
__global__ __launch_bounds__(256, 3) void argmin_kernel(
    const _Float16* __restrict__ zPack, const _Float16* __restrict__ wPack,
    const float* __restrict__ wn, u64* __restrict__ keys)
{
    __shared__ _Float16 zhi[128 * 32], zlo[128 * 32];   // 8 KB each
    __shared__ _Float16 whi[128 * 32], wlo[128 * 32];   // 8 KB each

    const int tid  = threadIdx.x;
    const int lane = tid & 63;
    const int wid  = tid >> 6;          // 0..3
    const int wm   = wid >> 1;          // token half (64)
    const int wq   = wid & 1;           // code half (64)
    const int t_   = blockIdx.x & 255;  // token tile
    const int q    = blockIdx.x >> 8;   // code eighth 0..7
    const int tok0  = t_ * 128;
    const int kbase = q * 128;

    const int n  = lane & 15;           // code/frag column
    const int kg = lane >> 4;           // k-group 0..3
    const int ga = kg ^ ((n ^ (n >> 2)) & 3);   // frag granule (row bits of n)

    float wnv[4];
    #pragma unroll
    for (int j = 0; j < 4; j++)
        wnv[j] = wn[kbase + wq * 64 + j * 16 + n];

    floatx4 acc[4][4];
    #pragma unroll
    for (int i = 0; i < 4; i++)
        #pragma unroll
        for (int j = 0; j < 4; j++)
            acc[i][j] = (floatx4){0.f, 0.f, 0.f, 0.f};

    for (int dt = 0; dt < 8; ++dt) {
        __syncthreads();   // previous chunk's fragment reads done
        // pure-copy staging: 4 arrays x 8 KB, images byte-identical to LDS
        {
            size_t zb = (size_t)(t_ * 8 + dt) * 8192;
            size_t wb = (size_t)(q  * 8 + dt) * 8192;
            #pragma unroll
            for (int j = 0; j < 2; j++) {
                int o = (j * 256 + tid) * 8;
                *(half8*)&zhi[o] = *(const half8*)&zPack[zb + o];
                *(half8*)&zlo[o] = *(const half8*)&zPack[zb + 4096 + o];
                *(half8*)&whi[o] = *(const half8*)&wPack[wb + o];
                *(half8*)&wlo[o] = *(const half8*)&wPack[wb + 4096 + o];
            }
        }
        __syncthreads();

        // fragments: A[m=n][k=kg*8+e], B[k][n]
        half8 ah[4], al[4];
        #pragma unroll
        for (int i = 0; i < 4; i++) {
            int off = (wm * 64 + i * 16 + n) * 32 + ga * 8;
            ah[i] = *(const half8*)&zhi[off];
            al[i] = *(const half8*)&zlo[off];
        }
        #pragma unroll
        for (int j = 0; j < 4; j++) {
            int off = (wq * 64 + j * 16 + n) * 32 + ga * 8;
            half8 bh = *(const half8*)&whi[off];
            half8 bl = *(const half8*)&wlo[off];
            #pragma unroll
            for (int i = 0; i < 4; i++) {
                acc[i][j] = __builtin_amdgcn_mfma_f32_16x16x32_f16(ah[i], bh, acc[i][j], 0, 0, 0);
                acc[i][j] = __builtin_amdgcn_mfma_f32_16x16x32_f16(ah[i], bl, acc[i][j], 0, 0, 0);
                acc[i][j] = __builtin_amdgcn_mfma_f32_16x16x32_f16(al[i], bh, acc[i][j], 0, 0, 0);
            }
        }
    }

    // epilogue: dist = wn[code] - 2*dot (||z||^2 constant per row).
    // C layout: col(code) = n, row(token) = kg*4 + reg.
    #pragma unroll
    for (int i = 0; i < 4; i++) {
        #pragma unroll
        for (int r = 0; r < 4; r++) {
            float bv = 3.4e38f; int bi = 0;
            #pragma unroll
            for (int j = 0; j < 4; j++) {
                float dist = wnv[j] - 2.0f * acc[i][j][r];
                if (dist < bv) { bv = dist; bi = kbase + wq * 64 + j * 16 + n; }
            }
            unsigned uu = __float_as_uint(bv);
            unsigned ss = (uu & 0x80000000u) ? ~uu : (uu | 0x80000000u);
            u64 key = ((u64)ss << 32) | (unsigned)bi;
            #pragma unroll
            for (int m = 1; m < 16; m <<= 1) {
                u64 o = __shfl_xor(key, m);
                if (o < key) key = o;
            }
            if (n == 0) {
                int token = tok0 + wm * 64 + i * 16 + kg * 4 + r;
                atomicMin(&keys[token], key);
            }
        }
    }
}

// ---------------- gather + commitment loss + idx/counts + fused finalize ----
// wave (64 lanes) = one token (64 float4). 8192 waves x 4 iters.
// Last block (device-scope done-counter) reduces counts+partials in-place,
// saving the finalize launch.
__global__ void gather_loss_kernel(const float* __restrict__ z,
                                   const float* __restrict__ w,
                                   const u64* __restrict__ keys,
                                   float* __restrict__ zq_out,
                                   float* __restrict__ idxf,
                                   int* __restrict__ counts,
                                   float* __restrict__ partials,
                                   unsigned* __restrict__ done,
                                   float* __restrict__ loss_out,
                                   float* __restrict__ ppl_out)
{
    __shared__ float red[4];
    __shared__ int lastBlk;
    int tid = threadIdx.x;
    int lane = tid & 63;
    int wid = blockIdx.x * 4 + (tid >> 6);   // 0..8191
    u64 k4[4];
    #pragma unroll
    for (int it = 0; it < 4; it++)
        k4[it] = keys[wid + it * 8192];
    float s = 0.0f;
    #pragma unroll
    for (int it = 0; it < 4; it++) {
        int tok = wid + it * 8192;
        int k = (int)(unsigned)(k4[it] & 0xFFFFFFFFull);
        float4 wv = *(const float4*)(w + (size_t)k * DIM + lane * 4);
        float4 zv = *(const float4*)(z + (size_t)tok * DIM + lane * 4);
        *(float4*)(zq_out + (size_t)tok * DIM + lane * 4) = wv;
        float dx = wv.x - zv.x, dy = wv.y - zv.y, dz = wv.z - zv.z, dw = wv.w - zv.w;
        s += dx * dx + dy * dy + dz * dz + dw * dw;
        if (lane == 0) {
            idxf[tok] = (float)k;
            atomicAdd(&counts[k], 1);
        }
    }
    #pragma unroll
    for (int off = 32; off; off >>= 1) s += __shfl_down(s, off);
    if (lane == 0) red[tid >> 6] = s;
    __syncthreads();
    if (tid == 0) {
        partials[blockIdx.x] = red[0] + red[1] + red[2] + red[3];
        __threadfence();
        unsigned old = atomicAdd(done, 1u);
        lastBlk = (old == gridDim.x - 1) ? 1 : 0;
    }
    __syncthreads();
    if (lastBlk) {
        __threadfence();
        float t = 0.f, p = 0.f;
        #pragma unroll
        for (int i = 0; i < 4; i++) {
            float e = (float)counts[tid * 4 + i] * (1.0f / (float)N_TOKENS);
            t += -e * logf(e + 1e-10f);
        }
        #pragma unroll
        for (int i = 0; i < 8; i++)
            p += partials[tid + i * 256];
        __shared__ float redE[4], redL[4];
        #pragma unroll
        for (int off = 32; off; off >>= 1) {
            t += __shfl_down(t, off);
            p += __shfl_down(p, off);
        }
        if (lane == 0) { redE[tid >> 6] = t; redL[tid >> 6] = p; }
        __syncthreads();
        if (tid == 0) {
            float se = redE[0] + redE[1] + redE[2] + redE[3];
            float sl = redL[0] + redL[1] + redL[2] + redL[3];
            *ppl_out = expf(se);
            *loss_out = BETA * sl / (float)((size_t)N_TOKENS * DIM);
        }
    }
}

extern "C" void kernel_launch(void* const* d_in, const int* in_sizes, int n_in,
                              void* d_out, int out_size, void* d_ws, size_t ws_size,
                              hipStream_t stream) {
    const float* z = (const float*)d_in[0];
    const float* w = (const float*)d_in[1];
    float* out = (float*)d_out;

    // d_out layout (float): [0]=loss, [1..NT*D]=z_q_st, [..]=indices(float), [last]=perplexity
    float* loss_out = out;
    float* zq_out   = out + 1;
    float* idxf     = out + 1 + (size_t)N_TOKENS * DIM;
    float* ppl_out  = out + (out_size - 1);

    // zPack (32 MB) lives in the z_q output region: dead scratch until gather
    // overwrites it. Byte offset 16 keeps 16-B alignment (d_out is 256-B
    // aligned); the 12-B tail overlap into idxf is rewritten by gather.
    _Float16* zPack = (_Float16*)((char*)d_out + 16);

    // ws layout (bytes): wn f32[1024] @0 | counts i32[1024] @4096
    //   | partials f32[2048] @8192 | done u32 @16384
    //   | keys u64[32768] @32768 | wPack fp16[524288] @294912  (~1.35 MB)
    float*    wn       = (float*)d_ws;
    int*      counts   = (int*)((char*)d_ws + 4096);
    float*    partials = (float*)((char*)d_ws + 8192);
    unsigned* done     = (unsigned*)((char*)d_ws + 16384);
    u64*      keys     = (u64*)((char*)d_ws + 32768);
    _Float16* wPack    = (_Float16*)((char*)d_ws + 294912);

    init_kernel<<<K_CODES, 64, 0, stream>>>(w, wn, counts, keys, done, wPack);
    prep_z_kernel<<<1024, 256, 0, stream>>>(z, zPack);
    argmin_kernel<<<8 * 256, 256, 0, stream>>>(zPack, wPack, wn, keys);
    gather_loss_kernel<<<2048, 256, 0, stream>>>(z, w, keys, zq_out, idxf,
                                                 counts, partials, done,
                                                 loss_out, ppl_out);
}